// Round 4
// baseline (9717.117 us; speedup 1.0000x reference)
//
#include <hip/hip_runtime.h>
#include <math.h>

#define NRAYS 262144
#define MAXIT 192
#define NEARV 0.2f
#define FARV  2.0f
#define EPSV  0.001f

// ---------------------------------------------------------------------------
// Kernel 1: sphere march. Persistent waves + atomic work-stealing,
// TWO rays per lane. All weight reads are wave-uniform loads from
// const __restrict__ global pointers -> scalar s_load (R2-proven path;
// R3 showed mixing LDS into the j-loop breaks scalarization -> VMEM).
// Rationale: R2 was scalar-pipe-bound at 52% VALU (16 KB of W1 s_loads per
// wave-step vs 8.7K VALU cyc). Two rays/lane doubles FMA per weight-read,
// halving SMEM demand per FLOP -> scalar pipe fully hidden, VALU-bound.
// Per-ray arithmetic is expression-identical to R1/R2 -> bit-exact.
// ---------------------------------------------------------------------------
__global__ __launch_bounds__(256, 3)
void march_kernel(const float* __restrict__ rays,
                  const float* __restrict__ W0, const float* __restrict__ b0,
                  const float* __restrict__ W1, const float* __restrict__ b1,
                  const float* __restrict__ W2, const float* __restrict__ b2,
                  float* __restrict__ t_out, int* __restrict__ hit_out,
                  int* __restrict__ counter)
{
    // slot 0
    float ox0 = 0.f, oy0 = 0.f, oz0 = 0.f, dx0 = 0.f, dy0 = 0.f, dz0 = 0.f;
    float cd0 = 0.f; int ridx0 = -1, it0 = 0; bool has0 = false, hit0 = false;
    // slot 1
    float ox1 = 0.f, oy1 = 0.f, oz1 = 0.f, dx1 = 0.f, dy1 = 0.f, dz1 = 0.f;
    float cd1 = 0.f; int ridx1 = -1, it1 = 0; bool has1 = false, hit1 = false;

    bool exhausted = false;
    const float b2_0 = b2[0];

    while (true) {
        if (!has0 && !exhausted) {
            int idx = atomicAdd(counter, 1);
            if (idx < NRAYS) {
                const float* r = rays + (size_t)idx * 6;
                ox0 = r[0]; oy0 = r[1]; oz0 = r[2];
                dx0 = r[3]; dy0 = r[4]; dz0 = r[5];
                cd0 = NEARV; it0 = 0; hit0 = false; has0 = true; ridx0 = idx;
            } else {
                exhausted = true;
            }
        }
        if (!has1 && !exhausted) {
            int idx = atomicAdd(counter, 1);
            if (idx < NRAYS) {
                const float* r = rays + (size_t)idx * 6;
                ox1 = r[0]; oy1 = r[1]; oz1 = r[2];
                dx1 = r[3]; dy1 = r[4]; dz1 = r[5];
                cd1 = NEARV; it1 = 0; hit1 = false; has1 = true; ridx1 = idx;
            } else {
                exhausted = true;
            }
        }
        if (__ballot(has0 || has1) == 0ull) break;

        // p = r_o + r_d * cd  (mul then add, matching numpy)
        const float px0 = ox0 + dx0 * cd0;
        const float py0 = oy0 + dy0 * cd0;
        const float pz0 = oz0 + dz0 * cd0;
        const float px1 = ox1 + dx1 * cd1;
        const float py1 = oy1 + dy1 * cd1;
        const float pz1 = oz1 + dz1 * cd1;

        float h1a[64], h1b[64];
        #pragma unroll
        for (int j = 0; j < 64; ++j) { h1a[j] = 0.f; h1b[j] = 0.f; }

        for (int k = 0; k < 64; ++k) {
            // uniform indices -> scalar loads, shared by both slots
            const float w0x = W0[k], w0y = W0[64 + k], w0z = W0[128 + k];
            const float bb = b0[k];
            float za = px0 * w0x + py0 * w0y + pz0 * w0z; za += bb;
            float zb = px1 * w0x + py1 * w0y + pz1 * w0z; zb += bb;
            const float aa = fmaxf(za, 0.f);
            const float ab = fmaxf(zb, 0.f);
            #pragma unroll
            for (int j = 0; j < 64; ++j) {
                const float w = W1[k * 64 + j];
                h1a[j] = fmaf(aa, w, h1a[j]);
                h1b[j] = fmaf(ab, w, h1b[j]);
            }
        }

        float d0 = 0.f, d1 = 0.f;
        #pragma unroll
        for (int j = 0; j < 64; ++j) {
            const float bj = b1[j];
            const float wj = W2[j * 33];
            d0 = fmaf(fmaxf(h1a[j] + bj, 0.f), wj, d0);
            d1 = fmaf(fmaxf(h1b[j] + bj, 0.f), wj, d1);
        }
        d0 += b2_0;
        d1 += b2_0;

        if (has0) {
            ++it0;
            if (d0 < EPSV && cd0 <= FARV) hit0 = true;
            cd0 += d0;
            if (hit0 || cd0 > FARV || it0 >= MAXIT) {
                t_out[ridx0] = cd0;
                hit_out[ridx0] = hit0 ? 1 : 0;
                has0 = false;
            }
        }
        if (has1) {
            ++it1;
            if (d1 < EPSV && cd1 <= FARV) hit1 = true;
            cd1 += d1;
            if (hit1 || cd1 > FARV || it1 >= MAXIT) {
                t_out[ridx1] = cd1;
                hit_out[ridx1] = hit1 ? 1 : 0;
                has1 = false;
            }
        }
    }
}

// ---------------------------------------------------------------------------
// Kernel 2: shading. One thread per ray. Only hit rays produce output.
// (Unchanged from R1/R2 passing version — bit-exact.)
// ---------------------------------------------------------------------------
__global__ __launch_bounds__(256, 2)
void shade_kernel(const float* __restrict__ rays,
                  const float* __restrict__ W0, const float* __restrict__ b0,
                  const float* __restrict__ W1, const float* __restrict__ b1,
                  const float* __restrict__ W2, const float* __restrict__ b2,
                  const float* __restrict__ RW0, const float* __restrict__ Rb0,
                  const float* __restrict__ RW1, const float* __restrict__ Rb1,
                  const float* __restrict__ t_in, const int* __restrict__ hit_in,
                  float* __restrict__ out)
{
    __shared__ float sW0[3 * 64];
    __shared__ float sb0[64];
    __shared__ float sW1[64 * 64];
    __shared__ float sb1[64];
    __shared__ float sW2T[33 * 64];   // [c][j] = W2[j][c]
    __shared__ float sb2[33];
    __shared__ float sRW0T[64 * 48];  // [u][f] = RW0[f][u], padded 41->48
    __shared__ float sRb0[64];
    __shared__ float sRW1[64 * 3];
    __shared__ float sRb1[3];

    const int tid = threadIdx.x;
    for (int i = tid; i < 3 * 64; i += 256) sW0[i] = W0[i];
    for (int i = tid; i < 64 * 64; i += 256) sW1[i] = W1[i];
    for (int i = tid; i < 33 * 64; i += 256) {
        const int c = i >> 6, j = i & 63;
        sW2T[i] = W2[j * 33 + c];
    }
    for (int i = tid; i < 64 * 41; i += 256) {
        const int u = i / 41, f = i - u * 41;
        sRW0T[u * 48 + f] = RW0[f * 64 + u];
    }
    if (tid < 64) { sb0[tid] = b0[tid]; sb1[tid] = b1[tid]; sRb0[tid] = Rb0[tid]; }
    if (tid < 33) sb2[tid] = b2[tid];
    if (tid < 192) sRW1[tid] = RW1[tid];
    if (tid < 3) sRb1[tid] = Rb1[tid];
    __syncthreads();

    const int i = blockIdx.x * 256 + tid;
    const bool hit = hit_in[i] != 0;

    // Whole-wave skip when nobody hit.
    if (__ballot(hit) == 0ull) {
        out[i * 3 + 0] = 0.f;
        out[i * 3 + 1] = 0.f;
        out[i * 3 + 2] = 0.f;
        return;
    }

    const float* r = rays + (size_t)i * 6;
    const float cd = t_in[i];
    const float ox = r[0], oy = r[1], oz = r[2];
    const float dx = r[3], dy = r[4], dz = r[5];
    const float px = ox + dx * cd;
    const float py = oy + dy * cd;
    const float pz = oz + dz * cd;

    // ---- forward, layer 1 accumulation (h0 recomputed on the fly) ----
    float h1[64];
    #pragma unroll
    for (int j = 0; j < 64; ++j) h1[j] = 0.f;

    for (int k = 0; k < 64; ++k) {
        float z = px * sW0[k] + py * sW0[64 + k] + pz * sW0[128 + k];
        z += sb0[k];
        const float a = fmaxf(z, 0.f);
        #pragma unroll
        for (int j = 0; j < 64; ++j) h1[j] = fmaf(a, sW1[k * 64 + j], h1[j]);
    }
    // rh1 = relu(h1 + b1)  (overwrite in place; rh1==0 <=> z1<=0)
    #pragma unroll
    for (int j = 0; j < 64; ++j) h1[j] = fmaxf(h1[j] + sb1[j], 0.f);

    // ---- latent = out[:,1:33] ----
    float lat[32];
    #pragma unroll
    for (int c = 1; c < 33; ++c) {
        float acc = 0.f;
        #pragma unroll
        for (int j = 0; j < 64; ++j) acc = fmaf(h1[j], sW2T[c * 64 + j], acc);
        lat[c - 1] = acc + sb2[c];
    }

    // ---- backward: gz1 = (z1>0) ? W2[:,0] : 0  (overwrite h1) ----
    #pragma unroll
    for (int j = 0; j < 64; ++j) h1[j] = (h1[j] > 0.f) ? sW2T[j] : 0.f;

    float nx = 0.f, ny = 0.f, nz = 0.f;
    for (int k = 0; k < 64; ++k) {
        float z = px * sW0[k] + py * sW0[64 + k] + pz * sW0[128 + k];
        z += sb0[k];
        float g = 0.f;
        #pragma unroll
        for (int j = 0; j < 64; ++j) g = fmaf(h1[j], sW1[k * 64 + j], g);
        if (z > 0.f) {
            nx = fmaf(g, sW0[k], nx);
            ny = fmaf(g, sW0[64 + k], ny);
            nz = fmaf(g, sW0[128 + k], nz);
        }
    }
    if (!hit) { nx = 0.f; ny = 0.f; nz = 0.f; }

    // ---- render MLP: feat(41) = [pts, r_d, nrm, latent] ----
    float r0 = 0.f, r1 = 0.f, r2 = 0.f;
    for (int u = 0; u < 64; ++u) {
        const float* w = &sRW0T[u * 48];
        float a = px * w[0] + py * w[1] + pz * w[2];
        a = fmaf(dx, w[3], a); a = fmaf(dy, w[4], a); a = fmaf(dz, w[5], a);
        a = fmaf(nx, w[6], a); a = fmaf(ny, w[7], a); a = fmaf(nz, w[8], a);
        #pragma unroll
        for (int q = 0; q < 32; ++q) a = fmaf(lat[q], w[9 + q], a);
        a += sRb0[u];
        const float ru = fmaxf(a, 0.f);
        r0 = fmaf(ru, sRW1[u * 3 + 0], r0);
        r1 = fmaf(ru, sRW1[u * 3 + 1], r1);
        r2 = fmaf(ru, sRW1[u * 3 + 2], r2);
    }
    r0 += sRb1[0]; r1 += sRb1[1]; r2 += sRb1[2];

    const float o0 = 1.f / (1.f + expf(-r0));
    const float o1 = 1.f / (1.f + expf(-r1));
    const float o2 = 1.f / (1.f + expf(-r2));

    out[i * 3 + 0] = hit ? o0 : 0.f;
    out[i * 3 + 1] = hit ? o1 : 0.f;
    out[i * 3 + 2] = hit ? o2 : 0.f;
}

extern "C" void kernel_launch(void* const* d_in, const int* in_sizes, int n_in,
                              void* d_out, int out_size, void* d_ws, size_t ws_size,
                              hipStream_t stream) {
    const float* rays = (const float*)d_in[0];
    const float* W0   = (const float*)d_in[1];
    const float* b0   = (const float*)d_in[2];
    const float* W1   = (const float*)d_in[3];
    const float* b1   = (const float*)d_in[4];
    const float* W2   = (const float*)d_in[5];
    const float* b2   = (const float*)d_in[6];
    const float* RW0  = (const float*)d_in[7];
    const float* Rb0  = (const float*)d_in[8];
    const float* RW1  = (const float*)d_in[9];
    const float* Rb1  = (const float*)d_in[10];

    // Workspace layout: t (N floats) | hit (N ints) | counter (1 int)
    float* t_ws  = (float*)d_ws;
    int* hit_ws  = (int*)d_ws + NRAYS;
    int* ctr     = (int*)d_ws + 2 * NRAYS;

    hipMemsetAsync(ctr, 0, sizeof(int), stream);

    // Persistent march: 2 rays/lane, 3 blocks/CU (VGPR-bound), work-stealing.
    march_kernel<<<768, 256, 0, stream>>>(rays, W0, b0, W1, b1, W2, b2,
                                          t_ws, hit_ws, ctr);

    shade_kernel<<<NRAYS / 256, 256, 0, stream>>>(rays, W0, b0, W1, b1, W2, b2,
                                                  RW0, Rb0, RW1, Rb1,
                                                  t_ws, hit_ws, (float*)d_out);
}

// Round 5
// 6842.775 us; speedup vs baseline: 1.4201x; 1.4201x over previous
//
#include <hip/hip_runtime.h>
#include <math.h>

#define NRAYS 262144
#define MAXIT 192
#define NEARV 0.2f
#define FARV  2.0f
#define EPSV  0.001f

typedef float v2f __attribute__((ext_vector_type(2)));

// ---------------------------------------------------------------------------
// Kernel 1: sphere march. Persistent waves + atomic work-stealing, 1 ray/lane
// (R2 structure). Weight reads are wave-uniform from const __restrict__
// global pointers -> scalar s_load (R2-proven; R3 showed LDS mixing breaks
// it, R4 showed 2 accum arrays trigger AGPR shuffle).
// NEW: the 64-wide h1 accumulation runs as 32 packed float2 chains ->
// v_pk_fma_f32, halving the dominant VALU instruction block. Each packed
// lane is the identical per-j serial fmaf chain -> bit-exact vs R2.
// R2/R4 evidence: duration ~ VALU inst count at fixed ~52% issue efficiency,
// so halving instructions should land ~3.4-4.0 ms.
// ---------------------------------------------------------------------------
__global__ __launch_bounds__(256, 4)
void march_kernel(const float* __restrict__ rays,
                  const float* __restrict__ W0, const float* __restrict__ b0,
                  const float* __restrict__ W1, const float* __restrict__ b1,
                  const float* __restrict__ W2, const float* __restrict__ b2,
                  float* __restrict__ t_out, int* __restrict__ hit_out,
                  int* __restrict__ counter)
{
    float ox = 0.f, oy = 0.f, oz = 0.f, rdx = 0.f, rdy = 0.f, rdz = 0.f;
    float cd = 0.f;
    int ridx = -1, it = 0;
    bool has = false, hit = false, exhausted = false;

    const float b2_0 = b2[0];
    const v2f* __restrict__ W1v = (const v2f* __restrict__)W1;  // rows of 32 float2

    while (true) {
        if (!has && !exhausted) {
            int idx = atomicAdd(counter, 1);
            if (idx < NRAYS) {
                const float* r = rays + (size_t)idx * 6;
                ox = r[0]; oy = r[1]; oz = r[2];
                rdx = r[3]; rdy = r[4]; rdz = r[5];
                cd = NEARV; it = 0; hit = false; has = true; ridx = idx;
            } else {
                exhausted = true;
            }
        }
        if (__ballot(has) == 0ull) break;

        // p = r_o + r_d * cd  (mul then add, matching numpy)
        const float px = ox + rdx * cd;
        const float py = oy + rdy * cd;
        const float pz = oz + rdz * cd;

        v2f h1v[32];
        #pragma unroll
        for (int m = 0; m < 32; ++m) h1v[m] = (v2f){0.f, 0.f};

        for (int k = 0; k < 64; ++k) {
            // uniform indices -> scalar loads
            float z = px * W0[k] + py * W0[64 + k] + pz * W0[128 + k];
            z += b0[k];
            const float a = fmaxf(z, 0.f);
            const v2f av = {a, a};
            #pragma unroll
            for (int m = 0; m < 32; ++m)
                h1v[m] = __builtin_elementwise_fma(av, W1v[k * 32 + m], h1v[m]);
        }

        // epilogue: identical scalar order j = 0..63 (bit-exact vs R2)
        float d = 0.f;
        #pragma unroll
        for (int m = 0; m < 32; ++m) {
            d = fmaf(fmaxf(h1v[m].x + b1[2 * m], 0.f),     W2[(2 * m) * 33],     d);
            d = fmaf(fmaxf(h1v[m].y + b1[2 * m + 1], 0.f), W2[(2 * m + 1) * 33], d);
        }
        d += b2_0;

        if (has) {
            ++it;
            if (d < EPSV && cd <= FARV) hit = true;
            cd += d;
            if (hit || cd > FARV || it >= MAXIT) {
                t_out[ridx] = cd;
                hit_out[ridx] = hit ? 1 : 0;
                has = false;
            }
        }
    }
}

// ---------------------------------------------------------------------------
// Kernel 2: shading. One thread per ray. Only hit rays produce output.
// (Unchanged from R1/R2 passing version — bit-exact.)
// ---------------------------------------------------------------------------
__global__ __launch_bounds__(256, 2)
void shade_kernel(const float* __restrict__ rays,
                  const float* __restrict__ W0, const float* __restrict__ b0,
                  const float* __restrict__ W1, const float* __restrict__ b1,
                  const float* __restrict__ W2, const float* __restrict__ b2,
                  const float* __restrict__ RW0, const float* __restrict__ Rb0,
                  const float* __restrict__ RW1, const float* __restrict__ Rb1,
                  const float* __restrict__ t_in, const int* __restrict__ hit_in,
                  float* __restrict__ out)
{
    __shared__ float sW0[3 * 64];
    __shared__ float sb0[64];
    __shared__ float sW1[64 * 64];
    __shared__ float sb1[64];
    __shared__ float sW2T[33 * 64];   // [c][j] = W2[j][c]
    __shared__ float sb2[33];
    __shared__ float sRW0T[64 * 48];  // [u][f] = RW0[f][u], padded 41->48
    __shared__ float sRb0[64];
    __shared__ float sRW1[64 * 3];
    __shared__ float sRb1[3];

    const int tid = threadIdx.x;
    for (int i = tid; i < 3 * 64; i += 256) sW0[i] = W0[i];
    for (int i = tid; i < 64 * 64; i += 256) sW1[i] = W1[i];
    for (int i = tid; i < 33 * 64; i += 256) {
        const int c = i >> 6, j = i & 63;
        sW2T[i] = W2[j * 33 + c];
    }
    for (int i = tid; i < 64 * 41; i += 256) {
        const int u = i / 41, f = i - u * 41;
        sRW0T[u * 48 + f] = RW0[f * 64 + u];
    }
    if (tid < 64) { sb0[tid] = b0[tid]; sb1[tid] = b1[tid]; sRb0[tid] = Rb0[tid]; }
    if (tid < 33) sb2[tid] = b2[tid];
    if (tid < 192) sRW1[tid] = RW1[tid];
    if (tid < 3) sRb1[tid] = Rb1[tid];
    __syncthreads();

    const int i = blockIdx.x * 256 + tid;
    const bool hit = hit_in[i] != 0;

    // Whole-wave skip when nobody hit.
    if (__ballot(hit) == 0ull) {
        out[i * 3 + 0] = 0.f;
        out[i * 3 + 1] = 0.f;
        out[i * 3 + 2] = 0.f;
        return;
    }

    const float* r = rays + (size_t)i * 6;
    const float cd = t_in[i];
    const float ox = r[0], oy = r[1], oz = r[2];
    const float dx = r[3], dy = r[4], dz = r[5];
    const float px = ox + dx * cd;
    const float py = oy + dy * cd;
    const float pz = oz + dz * cd;

    // ---- forward, layer 1 accumulation (h0 recomputed on the fly) ----
    float h1[64];
    #pragma unroll
    for (int j = 0; j < 64; ++j) h1[j] = 0.f;

    for (int k = 0; k < 64; ++k) {
        float z = px * sW0[k] + py * sW0[64 + k] + pz * sW0[128 + k];
        z += sb0[k];
        const float a = fmaxf(z, 0.f);
        #pragma unroll
        for (int j = 0; j < 64; ++j) h1[j] = fmaf(a, sW1[k * 64 + j], h1[j]);
    }
    // rh1 = relu(h1 + b1)  (overwrite in place; rh1==0 <=> z1<=0)
    #pragma unroll
    for (int j = 0; j < 64; ++j) h1[j] = fmaxf(h1[j] + sb1[j], 0.f);

    // ---- latent = out[:,1:33] ----
    float lat[32];
    #pragma unroll
    for (int c = 1; c < 33; ++c) {
        float acc = 0.f;
        #pragma unroll
        for (int j = 0; j < 64; ++j) acc = fmaf(h1[j], sW2T[c * 64 + j], acc);
        lat[c - 1] = acc + sb2[c];
    }

    // ---- backward: gz1 = (z1>0) ? W2[:,0] : 0  (overwrite h1) ----
    #pragma unroll
    for (int j = 0; j < 64; ++j) h1[j] = (h1[j] > 0.f) ? sW2T[j] : 0.f;

    float nx = 0.f, ny = 0.f, nz = 0.f;
    for (int k = 0; k < 64; ++k) {
        float z = px * sW0[k] + py * sW0[64 + k] + pz * sW0[128 + k];
        z += sb0[k];
        float g = 0.f;
        #pragma unroll
        for (int j = 0; j < 64; ++j) g = fmaf(h1[j], sW1[k * 64 + j], g);
        if (z > 0.f) {
            nx = fmaf(g, sW0[k], nx);
            ny = fmaf(g, sW0[64 + k], ny);
            nz = fmaf(g, sW0[128 + k], nz);
        }
    }
    if (!hit) { nx = 0.f; ny = 0.f; nz = 0.f; }

    // ---- render MLP: feat(41) = [pts, r_d, nrm, latent] ----
    float r0 = 0.f, r1 = 0.f, r2 = 0.f;
    for (int u = 0; u < 64; ++u) {
        const float* w = &sRW0T[u * 48];
        float a = px * w[0] + py * w[1] + pz * w[2];
        a = fmaf(dx, w[3], a); a = fmaf(dy, w[4], a); a = fmaf(dz, w[5], a);
        a = fmaf(nx, w[6], a); a = fmaf(ny, w[7], a); a = fmaf(nz, w[8], a);
        #pragma unroll
        for (int q = 0; q < 32; ++q) a = fmaf(lat[q], w[9 + q], a);
        a += sRb0[u];
        const float ru = fmaxf(a, 0.f);
        r0 = fmaf(ru, sRW1[u * 3 + 0], r0);
        r1 = fmaf(ru, sRW1[u * 3 + 1], r1);
        r2 = fmaf(ru, sRW1[u * 3 + 2], r2);
    }
    r0 += sRb1[0]; r1 += sRb1[1]; r2 += sRb1[2];

    const float o0 = 1.f / (1.f + expf(-r0));
    const float o1 = 1.f / (1.f + expf(-r1));
    const float o2 = 1.f / (1.f + expf(-r2));

    out[i * 3 + 0] = hit ? o0 : 0.f;
    out[i * 3 + 1] = hit ? o1 : 0.f;
    out[i * 3 + 2] = hit ? o2 : 0.f;
}

extern "C" void kernel_launch(void* const* d_in, const int* in_sizes, int n_in,
                              void* d_out, int out_size, void* d_ws, size_t ws_size,
                              hipStream_t stream) {
    const float* rays = (const float*)d_in[0];
    const float* W0   = (const float*)d_in[1];
    const float* b0   = (const float*)d_in[2];
    const float* W1   = (const float*)d_in[3];
    const float* b1   = (const float*)d_in[4];
    const float* W2   = (const float*)d_in[5];
    const float* b2   = (const float*)d_in[6];
    const float* RW0  = (const float*)d_in[7];
    const float* Rb0  = (const float*)d_in[8];
    const float* RW1  = (const float*)d_in[9];
    const float* Rb1  = (const float*)d_in[10];

    // Workspace layout: t (N floats) | hit (N ints) | counter (1 int)
    float* t_ws  = (float*)d_ws;
    int* hit_ws  = (int*)d_ws + NRAYS;
    int* ctr     = (int*)d_ws + 2 * NRAYS;

    hipMemsetAsync(ctr, 0, sizeof(int), stream);

    // Persistent march: 4 blocks/CU, 1 ray/lane (262144 = 1024*256 exactly).
    march_kernel<<<1024, 256, 0, stream>>>(rays, W0, b0, W1, b1, W2, b2,
                                           t_ws, hit_ws, ctr);

    shade_kernel<<<NRAYS / 256, 256, 0, stream>>>(rays, W0, b0, W1, b1, W2, b2,
                                                  RW0, Rb0, RW1, Rb1,
                                                  t_ws, hit_ws, (float*)d_out);
}